// Round 12
// baseline (112.514 us; speedup 1.0000x reference)
//
#include <hip/hip_runtime.h>
#include <hip/hip_fp16.h>

#define OUT_H 512
#define OUT_W 512
#define BATCH 64
#define CHANS 3

#define WROWS 48
#define WPX   48
// Row-interleaved f16 planes in ONE array: source row r -> A{c0,c1} at
// slot 98r+lx, B{c2,0} at 98r+49+lx. All 8 corner dwords of a pixel are at
// base + {0,1,49,50,98,99,147,148} -> one vaddr, 4x ds_read2_b32.
#define RSTRIDE 98
#define LSZ 4704
#define IDXMAX (LSZ - 149)

struct Win {
    float xb0, yb0;
    int bx, by;
    bool interior;
};

__device__ __forceinline__ Win make_win(float xb0, float yb0, float c, float s) {
    float xmin = xb0 + fminf(0.0f, 31.0f * c) + fminf(0.0f, -31.0f * s);
    float ymin = yb0 + fminf(0.0f, 31.0f * s) + fminf(0.0f,  31.0f * c);
    float xmax = xb0 + fmaxf(0.0f, 31.0f * c) + fmaxf(0.0f, -31.0f * s);
    float ymax = yb0 + fmaxf(0.0f, 31.0f * s) + fmaxf(0.0f,  31.0f * c);
    Win w;
    int bx0 = min(max((int)floorf(xmin), 0), OUT_W - 1);
    int by0 = min(max((int)floorf(ymin), 0), OUT_H - 1);
    w.bx = min(bx0, OUT_W - WPX);
    w.by = min(by0, OUT_H - WROWS);
    w.interior = (xmin >= 0.0f) & (xmax < 510.0f) &
                 (ymin >= 0.0f) & (ymax < 510.0f);
    w.xb0 = xb0; w.yb0 = yb0;
    return w;
}

// Stage loads: 9 overlapping dwordx4 per thread (16B load shifted 4B back so
// {c0,c1,c2} = .y.z.w). OOB-low only possible for the b==0 origin window.
__device__ __forceinline__ void stage_load(const float* __restrict__ Ub,
                                           const Win& w, int tid, bool origin,
                                           float4 va[9]) {
    const float* gb = Ub + ((size_t)w.by * OUT_W + w.bx) * CHANS;
    if (!origin) {
#pragma unroll
        for (int k = 0; k < 9; ++k) {
            unsigned q = (unsigned)tid + 256u * k;
            unsigned r  = q / 48u;
            unsigned lx = q - r * 48u;
            va[k] = *(const float4*)(gb + (size_t)r * (OUT_W * CHANS) + lx * 3u - 1);
        }
    } else {
#pragma unroll
        for (int k = 0; k < 9; ++k) {
            unsigned q = (unsigned)tid + 256u * k;
            unsigned r  = q / 48u;
            unsigned lx = q - r * 48u;
            const float* p = gb + (size_t)r * (OUT_W * CHANS) + lx * 3u;
            float2 ab = *(const float2*)p;
            float  cc = p[2];
            va[k] = make_float4(0.0f, ab.x, ab.y, cc);
        }
    }
}

__device__ __forceinline__ void stage_write(unsigned int* smf, int tid,
                                            const float4 va[9]) {
#pragma unroll
    for (int k = 0; k < 9; ++k) {
        unsigned q = (unsigned)tid + 256u * k;
        unsigned r  = q / 48u;
        unsigned lx = q - r * 48u;
        unsigned slot = RSTRIDE * r + lx;           // lane-stride 1, conflict-free
        float4 v = va[k];
        __half2 hA = __floats2half2_rn(v.y, v.z);   // {c0,c1}
        __half2 hB = __floats2half2_rn(v.w, 0.0f);  // {c2,0}
        smf[slot]      = *(const unsigned int*)&hA; // ds_write2_b32 {0,49}
        smf[slot + 49] = *(const unsigned int*)&hB;
    }
}

__device__ __forceinline__ void compute_store(const unsigned int* smf,
                                              const Win& w, float c, float s,
                                              int tid, float* __restrict__ po) {
    int il = tid >> 3;                  // 0..31
    int jb = (tid & 7) << 2;            // 0,4,...,28
    float xr = w.xb0 + c * (float)jb - s * (float)il;
    float yr = w.yb0 + s * (float)jb + c * (float)il;
    int Koff = w.by * RSTRIDE + w.bx;
    bool interior = w.interior;

    float o[12];
#pragma unroll
    for (int p = 0; p < 4; ++p) {
        float x = fmaf(c, (float)p, xr);
        float y = fmaf(s, (float)p, yr);
        int ix = __float2int_rd(x);
        int iy = __float2int_rd(y);
        float fx = x - (float)ix;
        float fy = y - (float)iy;

        int idx = iy * RSTRIDE + ix - Koff;
        if (!interior) idx = min(max(idx, 0), IDXMAX);  // v_med3; masked safe

        const unsigned int* lp = smf + idx;             // ONE vaddr, 4x ds_read2
        unsigned iA0 = lp[0],   iA1 = lp[1];
        unsigned iB0 = lp[49],  iB1 = lp[50];
        unsigned iA2 = lp[98],  iA3 = lp[99];
        unsigned iB2 = lp[147], iB3 = lp[148];

        __half2 fx2 = __float2half2_rn(fx);
        __half2 fy2 = __float2half2_rn(fy);
        __half2 a01 = *(const __half2*)&iA0, c01 = *(const __half2*)&iA1;
        __half2 a2  = *(const __half2*)&iB0, c2  = *(const __half2*)&iB1;
        __half2 b01 = *(const __half2*)&iA2, d01 = *(const __half2*)&iA3;
        __half2 b2  = *(const __half2*)&iB2, d2  = *(const __half2*)&iB3;

        __half2 t01 = __hfma2(fx2, __hsub2(c01, a01), a01);
        __half2 t2  = __hfma2(fx2, __hsub2(c2,  a2),  a2);
        __half2 u01 = __hfma2(fx2, __hsub2(d01, b01), b01);
        __half2 u2  = __hfma2(fx2, __hsub2(d2,  b2),  b2);
        __half2 r01 = __hfma2(fy2, __hsub2(u01, t01), t01);
        __half2 r2  = __hfma2(fy2, __hsub2(u2,  t2),  t2);

        float v0 = __low2float(r01);
        float v1 = __high2float(r01);
        float v2 = __low2float(r2);
        if (!interior) {
            // Reference yields exactly 0 where clamped corners collapse.
            bool valid = ((unsigned)ix < 511u) & ((unsigned)iy < 511u);
            v0 = valid ? v0 : 0.0f;
            v1 = valid ? v1 : 0.0f;
            v2 = valid ? v2 : 0.0f;
        }
        o[p * 3 + 0] = v0;
        o[p * 3 + 1] = v1;
        o[p * 3 + 2] = v2;
    }

    float* pr = po + (size_t)il * (OUT_W * CHANS) + jb * CHANS;
    ((float4*)pr)[0] = make_float4(o[0], o[1], o[2],  o[3]);
    ((float4*)pr)[1] = make_float4(o[4], o[5], o[6],  o[7]);
    ((float4*)pr)[2] = make_float4(o[8], o[9], o[10], o[11]);
}

__global__ __launch_bounds__(256) void st_bilinear_kernel(
    const float* __restrict__ U,      // [B, H, W, C] f32
    const float* __restrict__ theta,  // [B, 1]
    float* __restrict__ out)          // [B, H, W, C] f32
{
    __shared__ __align__(16) unsigned int smf[LSZ];

    // 8192 blocks, 2 horizontally-adjacent tiles each. XCD-aware remap:
    // XCD k gets images [k*8, k*8+8) (image = 3.1 MB, fits 4 MB L2).
    int blk  = blockIdx.x;
    int lp   = (blk & 7) * 1024 + (blk >> 3);   // pair index, bijective
    int b    = lp >> 7;                         // image (uniform per block)
    int pair = lp & 127;                        // 8 pairs/row x 16 rows
    int tr   = pair >> 3;
    int i0   = tr << 5;
    int j0A  = ((pair & 7) << 1) << 5;          // tile A col origin
    int tid  = threadIdx.x;

    float tt = theta[__builtin_amdgcn_readfirstlane(b)];
    float s, c;
    __sincosf(tt, &s, &c);

    // x = xb0 + c*jl - s*il ; y = yb0 + s*jl + c*il  ((2/511)*255.5 == 1)
    const float scale = 2.0f / 511.0f;
    float gx0 = (float)j0A * scale - 1.0f;
    float gy0 = (float)i0  * scale - 1.0f;
    float xb0A = (c * gx0 - s * gy0 + 1.0f) * 255.5f;
    float yb0A = (s * gx0 + c * gy0 + 1.0f) * 255.5f;

    Win wA = make_win(xb0A, yb0A, c, s);
    Win wB = make_win(xb0A + 32.0f * c, yb0A + 32.0f * s, c, s);  // tile B = A shifted 32 cols

    const float* Ub = U + (size_t)b * (OUT_H * OUT_W * CHANS);
    bool b0 = (b == 0);

    // ---- pipeline: loadA -> writeA -> loadB (in flight) -> computeA -> writeB -> computeB
    float4 va[9];
    stage_load(Ub, wA, tid, b0 & (wA.bx == 0) & (wA.by == 0), va);
    stage_write(smf, tid, va);

    float4 vb[9];
    stage_load(Ub, wB, tid, b0 & (wB.bx == 0) & (wB.by == 0), vb);  // hides under compute A

    __syncthreads();                                  // LDS-A ready

    float* poA = out + (((size_t)b * OUT_H + i0) * OUT_W + j0A) * CHANS;
    compute_store(smf, wA, c, s, tid, poA);

    __syncthreads();                                  // all waves done reading A

    stage_write(smf, tid, vb);                        // vmcnt wait ~0 (loads long landed)

    __syncthreads();                                  // LDS-B ready

    compute_store(smf, wB, c, s, tid, poA + 32 * CHANS);
}

extern "C" void kernel_launch(void* const* d_in, const int* in_sizes, int n_in,
                              void* d_out, int out_size, void* d_ws, size_t ws_size,
                              hipStream_t stream) {
    const float* U     = (const float*)d_in[0];
    const float* theta = (const float*)d_in[1];
    float* out = (float*)d_out;

    int blocks = BATCH * (OUT_H / 32) * (OUT_W / 32) / 2;   // 8192
    st_bilinear_kernel<<<blocks, 256, 0, stream>>>(U, theta, out);
}